// Round 9
// baseline (428.332 us; speedup 1.0000x reference)
//
#include <hip/hip_runtime.h>
#include <hip/hip_fp16.h>
#include <hip/hip_cooperative_groups.h>

namespace cg = cooperative_groups;

// GCN encoder on MI355X. One cooperative kernel builds the CSR (zero, hist,
// scan, fill, W1^T prep) with grid.sync() between phases -> 4 dispatches total.
// fp16 activations; 4-byte edge records {w:fp16 | src:u16}; scalar record
// loads; one-edge-row-per-load-instruction gathers (round-7 structure, proven);
// MFMA layer-1 GEMM; LN/ReLU/W2/L2 epilogues fused into the gathers.

#define K_DIM 128

typedef _Float16 f16x8 __attribute__((ext_vector_type(8)));
typedef _Float16 f16x4 __attribute__((ext_vector_type(4)));
typedef float f32x4 __attribute__((ext_vector_type(4)));

// ---------- cooperative CSR build ----------
// P0: zero counts + edge pad, W1->WT(fp16 transposed)
// P1: hist (atomics)   P2: per-chunk scan + dinv   P3: partials scan   P4: fill
__global__ __launch_bounds__(256) void csr_build_kernel(
    const int* __restrict__ src, const int* __restrict__ dst,
    int* counts, int* row_ptr, int* partials, float* dinv,
    unsigned int* edges, const float* __restrict__ W1, _Float16* WT,
    int N, int E) {
    __shared__ int sm[256];
    cg::grid_group grid = cg::this_grid();
    const int tid = blockIdx.x * 256 + threadIdx.x;
    const int nthreads = gridDim.x * 256;
    const int t = threadIdx.x;

    // P0
    for (int i = tid; i < N; i += nthreads) counts[i] = 0;
    if (tid < 64) edges[E + tid] = 0;
    for (int i = tid; i < 128 * 128; i += nthreads) {
        int k = i >> 7, j = i & 127;
        WT[j * 128 + k] = (_Float16)W1[i];
    }
    grid.sync();

    // P1
    for (int i = tid; i < E; i += nthreads) atomicAdd(&counts[dst[i]], 1);
    grid.sync();

    // P2: block-local exclusive scan per 256-chunk; partials[c] = chunk total
    const int nchunks = (N + 255) / 256;   // 196 (must be <= 256)
    for (int c = blockIdx.x; c < nchunks; c += gridDim.x) {
        int i = c * 256 + t;
        int v = (i < N) ? counts[i] : 0;
        if (i < N) dinv[i] = rsqrtf((float)(v + 1));  // +1 self-loop
        sm[t] = v;
        __syncthreads();
        for (int off = 1; off < 256; off <<= 1) {
            int add = (t >= off) ? sm[t - off] : 0;
            __syncthreads();
            sm[t] += add;
            __syncthreads();
        }
        if (i < N) row_ptr[i] = sm[t] - v;
        if (t == 255) partials[c] = sm[255];
        __syncthreads();
    }
    grid.sync();

    // P3: exclusive scan of partials (single block)
    if (blockIdx.x == 0) {
        int v = (t < nchunks) ? partials[t] : 0;
        sm[t] = v;
        __syncthreads();
        for (int off = 1; off < 256; off <<= 1) {
            int add = (t >= off) ? sm[t - off] : 0;
            __syncthreads();
            sm[t] += add;
            __syncthreads();
        }
        if (t < nchunks) partials[t] = sm[t] - v;
    }
    grid.sync();

    // P4: fill. row_ptr[d] is block-local cursor; global pos = cursor + partials[d>>8].
    for (int i = tid; i < E; i += nthreads) {
        int d = dst[i];
        int s = src[i];
        int pos = atomicAdd(&row_ptr[d], 1) + partials[d >> 8];
        float w = dinv[s] * dinv[d];
        edges[pos] = ((unsigned int)__half_as_ushort(__float2half_rn(w)) << 16)
                   | (unsigned int)s;
    }
}

// ---------- GEMM1 (MFMA): h1 = X @ W1, f16 out ----------
__global__ __launch_bounds__(256) void gemm1_mfma_kernel(const float* __restrict__ X,
                                                         const _Float16* __restrict__ WT,
                                                         __half* __restrict__ H, int N) {
    __shared__ _Float16 As[64][136];

    int row0 = blockIdx.x * 64;
    {
        int r = threadIdx.x >> 2;
        int c0 = (threadIdx.x & 3) * 32;
        int row = row0 + r;
        if (row < N) {
            const float4* srcp = (const float4*)(X + (size_t)row * 128 + c0);
#pragma unroll
            for (int i = 0; i < 8; ++i) {
                float4 v = srcp[i];
                f16x4 h = {(_Float16)v.x, (_Float16)v.y, (_Float16)v.z, (_Float16)v.w};
                *(f16x4*)&As[r][c0 + 4 * i] = h;
            }
        } else {
            f16x4 z = {};
#pragma unroll
            for (int i = 0; i < 8; ++i) *(f16x4*)&As[r][c0 + 4 * i] = z;
        }
    }
    __syncthreads();

    int wave = threadIdx.x >> 6;
    int lane = threadIdx.x & 63;
    int l15 = lane & 15;
    int k0 = (lane >> 4) * 8;
    int arow = wave * 16 + l15;

    f32x4 acc[8] = {};
#pragma unroll
    for (int ks = 0; ks < 4; ++ks) {
        f16x8 a = *(const f16x8*)&As[arow][ks * 32 + k0];
#pragma unroll
        for (int t = 0; t < 8; ++t) {
            f16x8 b = *(const f16x8*)(WT + (size_t)(t * 16 + l15) * 128 + ks * 32 + k0);
            acc[t] = __builtin_amdgcn_mfma_f32_16x16x32_f16(a, b, acc[t], 0, 0, 0);
        }
    }

    int rbase = row0 + wave * 16 + (lane >> 4) * 4;
#pragma unroll
    for (int t = 0; t < 8; ++t) {
#pragma unroll
        for (int r = 0; r < 4; ++r) {
            int row = rbase + r;
            if (row < N) H[(size_t)row * 128 + t * 16 + l15] = __float2half(acc[t][r]);
        }
    }
}

// ---------- gather1 fused: agg(h1) -> +b1 -> LN -> ReLU -> @W2 -> h3 (fp16) ----------
__global__ __launch_bounds__(256) void gather1_fused_kernel(
    const __half* __restrict__ h1, const float* __restrict__ dinv,
    const int* __restrict__ row_ptr, const int* __restrict__ counts,
    const int* __restrict__ partials, const unsigned int* __restrict__ edges,
    const float* __restrict__ b1, const float* __restrict__ g1,
    const float* __restrict__ beta1, const float* __restrict__ W2,
    __half* __restrict__ h3, int N) {
    __shared__ float lds[4][K_DIM];
    int wave = threadIdx.x >> 6;
    int lane = threadIdx.x & 63;
    int node = blockIdx.x * 4 + wave;
    if (node >= N) return;

    float dd = dinv[node];
    float2 acc = __half22float2(((const __half2*)(h1 + (size_t)node * 128))[lane]);
    acc.x *= dd * dd; acc.y *= dd * dd;

    int end = row_ptr[node] + partials[node >> 8];
    int beg = end - counts[node];
    beg = __builtin_amdgcn_readfirstlane(beg);
    end = __builtin_amdgcn_readfirstlane(end);

    for (int e = beg; e < end; e += 8) {
        unsigned int rec[8];
#pragma unroll
        for (int i = 0; i < 8; ++i) rec[i] = edges[e + i];   // uniform -> s_load
        __half2 v[8];
#pragma unroll
        for (int i = 0; i < 8; ++i)
            v[i] = ((const __half2*)(h1 + (size_t)(rec[i] & 0xFFFFu) * 128))[lane];
#pragma unroll
        for (int i = 0; i < 8; ++i) {
            float w = (e + i < end)
                          ? __half2float(__ushort_as_half((unsigned short)(rec[i] >> 16)))
                          : 0.0f;
            float2 f = __half22float2(v[i]);
            acc.x = fmaf(f.x, w, acc.x);
            acc.y = fmaf(f.y, w, acc.y);
        }
    }

    // bias + LN + ReLU
    float2 bb = ((const float2*)b1)[lane];
    acc.x += bb.x; acc.y += bb.y;
    float s = acc.x + acc.y;
    for (int off = 32; off; off >>= 1) s += __shfl_xor(s, off);
    float mu = s * (1.0f / 128.0f);
    float dx = acc.x - mu, dy = acc.y - mu;
    float q = dx * dx + dy * dy;
    for (int off = 32; off; off >>= 1) q += __shfl_xor(q, off);
    float rstd = rsqrtf(q * (1.0f / 128.0f) + 1e-5f);
    float2 gg = ((const float2*)g1)[lane];
    float2 be = ((const float2*)beta1)[lane];
    float ox = fmaxf(fmaf(dx * rstd, gg.x, be.x), 0.0f);
    float oy = fmaxf(fmaf(dy * rstd, gg.y, be.y), 0.0f);

    // 128x64 matvec via LDS broadcast; lane owns output col = lane
    ((float2*)&lds[wave][0])[lane] = make_float2(ox, oy);
    float o = 0.0f;
#pragma unroll 8
    for (int k = 0; k < K_DIM; k += 4) {
        float4 vv = *(const float4*)&lds[wave][k];
        o = fmaf(vv.x, W2[(size_t)(k + 0) * 64 + lane], o);
        o = fmaf(vv.y, W2[(size_t)(k + 1) * 64 + lane], o);
        o = fmaf(vv.z, W2[(size_t)(k + 2) * 64 + lane], o);
        o = fmaf(vv.w, W2[(size_t)(k + 3) * 64 + lane], o);
    }
    h3[(size_t)node * 64 + lane] = __float2half(o);
}

// ---------- gather2 fused: agg(h3) -> +b2 -> LN -> ReLU -> L2 -> out ----------
__global__ __launch_bounds__(256) void gather2_fused_kernel(
    const __half* __restrict__ h3, const float* __restrict__ dinv,
    const int* __restrict__ row_ptr, const int* __restrict__ counts,
    const int* __restrict__ partials, const unsigned int* __restrict__ edges,
    const float* __restrict__ b2, const float* __restrict__ g2,
    const float* __restrict__ beta2, float* __restrict__ out, int N) {
    int wave = threadIdx.x >> 6;
    int lane = threadIdx.x & 63;
    int node = blockIdx.x * 4 + wave;
    if (node >= N) return;

    float dd = dinv[node];
    float acc = __half2float(h3[(size_t)node * 64 + lane]) * dd * dd;

    int end = row_ptr[node] + partials[node >> 8];
    int beg = end - counts[node];
    beg = __builtin_amdgcn_readfirstlane(beg);
    end = __builtin_amdgcn_readfirstlane(end);

    for (int e = beg; e < end; e += 8) {
        unsigned int rec[8];
#pragma unroll
        for (int i = 0; i < 8; ++i) rec[i] = edges[e + i];
        __half v[8];
#pragma unroll
        for (int i = 0; i < 8; ++i)
            v[i] = h3[(size_t)(rec[i] & 0xFFFFu) * 64 + lane];
#pragma unroll
        for (int i = 0; i < 8; ++i) {
            float w = (e + i < end)
                          ? __half2float(__ushort_as_half((unsigned short)(rec[i] >> 16)))
                          : 0.0f;
            acc = fmaf(__half2float(v[i]), w, acc);
        }
    }

    float v = acc + b2[lane];
    float s = v;
    for (int off = 32; off; off >>= 1) s += __shfl_xor(s, off);
    float mu = s * (1.0f / 64.0f);
    float d = v - mu;
    float q = d * d;
    for (int off = 32; off; off >>= 1) q += __shfl_xor(q, off);
    float rstd = rsqrtf(q * (1.0f / 64.0f) + 1e-5f);
    float o = fmaxf(fmaf(d * rstd, g2[lane], beta2[lane]), 0.0f);
    float q2 = o * o;
    for (int off = 32; off; off >>= 1) q2 += __shfl_xor(q2, off);
    float nrm = sqrtf(q2);
    out[(size_t)node * 64 + lane] = o / fmaxf(nrm, 1e-12f);
}

extern "C" void kernel_launch(void* const* d_in, const int* in_sizes, int n_in,
                              void* d_out, int out_size, void* d_ws, size_t ws_size,
                              hipStream_t stream) {
    const float* x     = (const float*)d_in[0];
    const int*   ei    = (const int*)d_in[1];
    const float* W1    = (const float*)d_in[2];
    const float* b1    = (const float*)d_in[3];
    const float* g1    = (const float*)d_in[4];
    const float* beta1 = (const float*)d_in[5];
    const float* W2    = (const float*)d_in[6];
    const float* b2    = (const float*)d_in[7];
    const float* g2    = (const float*)d_in[8];
    const float* beta2 = (const float*)d_in[9];

    const int N = in_sizes[0] / 128;
    const int E = in_sizes[1] / 2;
    const int* src = ei;       // edge_index[0]
    const int* dst = ei + E;   // edge_index[1]
    float* out = (float*)d_out;

    // Workspace (~23 MB)
    char* p = (char*)d_ws;
    auto alloc = [&](size_t bytes) { char* r = p; p += (bytes + 255) & ~(size_t)255; return r; };
    int*          counts   = (int*)alloc((size_t)N * 4);
    int*          row_ptr  = (int*)alloc((size_t)N * 4);
    int*          partials = (int*)alloc(256 * 4);
    float*        dinv     = (float*)alloc((size_t)N * 4);
    unsigned int* edges    = (unsigned int*)alloc(((size_t)E + 64) * 4);  // +pad
    _Float16*     WT       = (_Float16*)alloc(128 * 128 * 2);
    __half*       h1       = (__half*)alloc((size_t)N * 128 * 2);
    __half*       h3       = (__half*)alloc((size_t)N * 64 * 2);

    const int nb_wave_nodes = (N + 3) / 4;

    // 1) cooperative CSR build (zero + hist + scan + fill + WT prep), 1 dispatch
    {
        void* args[] = {(void*)&src, (void*)&dst, (void*)&counts, (void*)&row_ptr,
                        (void*)&partials, (void*)&dinv, (void*)&edges,
                        (void*)&W1, (void*)&WT, (void*)&N, (void*)&E};
        hipLaunchCooperativeKernel((void*)csr_build_kernel, dim3(512), dim3(256),
                                   args, 0, stream);
    }

    // 2) layer 1 GEMM (MFMA, f16 out)
    gemm1_mfma_kernel<<<(N + 63) / 64, 256, 0, stream>>>(x, WT, h1, N);

    // 3) layer 1 aggregate + LN + ReLU + layer 2 GEMM (fused)
    gather1_fused_kernel<<<nb_wave_nodes, 256, 0, stream>>>(
        h1, dinv, row_ptr, counts, partials, edges, b1, g1, beta1, W2, h3, N);

    // 4) layer 2 aggregate + LN + ReLU + L2 (fused)
    gather2_fused_kernel<<<nb_wave_nodes, 256, 0, stream>>>(
        h3, dinv, row_ptr, counts, partials, edges, b2, g2, beta2, out, N);
}

// Round 10
// 209.259 us; speedup vs baseline: 2.0469x; 2.0469x over previous
//
#include <hip/hip_runtime.h>
#include <hip/hip_fp16.h>

// GCN encoder on MI355X. CSR (counting sort by dst) + fused gather aggregation.
// fp16 activations; 4-byte edge records {w:fp16 | src:u16} (N=50000 < 2^16);
// scalar (wave-uniform) record loads; ONE edge row per load instruction
// (multi-row loads regressed, round 8); main loop = 16 unpredicated row loads
// in flight (MLP), tail loop = 8 predicated. MFMA layer-1 GEMM; LN/ReLU/W2/L2
// epilogues fused into the gathers. Cooperative grid.sync rejected (round 9:
// ~70us per sync at 512 blocks).

#define K_DIM 128

typedef _Float16 f16x8 __attribute__((ext_vector_type(8)));
typedef _Float16 f16x4 __attribute__((ext_vector_type(4)));
typedef float f32x4 __attribute__((ext_vector_type(4)));

__device__ __forceinline__ float wbits(unsigned int r) {
    return __half2float(__ushort_as_half((unsigned short)(r >> 16)));
}

// ---------- CSR build ----------
__global__ __launch_bounds__(256) void hist_kernel(const int* __restrict__ dst,
                                                   int* counts, int E) {
    int i = blockIdx.x * 256 + threadIdx.x;
    if (i < E) atomicAdd(&counts[dst[i]], 1);
}

__global__ __launch_bounds__(256) void scan_block_kernel(const int* __restrict__ counts,
                                                         int* row_ptr, int* partials,
                                                         float* dinv, int N) {
    __shared__ int sm[256];
    int t = threadIdx.x;
    int i = blockIdx.x * 256 + t;
    int v = (i < N) ? counts[i] : 0;
    if (i < N) dinv[i] = rsqrtf((float)(v + 1));
    sm[t] = v;
    __syncthreads();
    for (int off = 1; off < 256; off <<= 1) {
        int add = (t >= off) ? sm[t - off] : 0;
        __syncthreads();
        sm[t] += add;
        __syncthreads();
    }
    if (i < N) row_ptr[i] = sm[t] - v;  // block-local exclusive
    if (t == 255) partials[blockIdx.x] = sm[255];
}

__global__ __launch_bounds__(256) void scan_partials_kernel(int* partials, int NB) {
    __shared__ int sm[256];
    int t = threadIdx.x;
    int v = (t < NB) ? partials[t] : 0;
    sm[t] = v;
    __syncthreads();
    for (int off = 1; off < 256; off <<= 1) {
        int add = (t >= off) ? sm[t - off] : 0;
        __syncthreads();
        sm[t] += add;
        __syncthreads();
    }
    if (t < NB) partials[t] = sm[t] - v;  // exclusive
}

// fill: row_ptr[d] is a block-local cursor; global pos = cursor + partials[d>>8].
__global__ __launch_bounds__(256) void fill_kernel(const int* __restrict__ src,
                                                   const int* __restrict__ dst,
                                                   const float* __restrict__ dinv,
                                                   int* row_ptr,
                                                   const int* __restrict__ partials,
                                                   unsigned int* edges, int E) {
    int i = blockIdx.x * 256 + threadIdx.x;
    if (i < E) {
        int d = dst[i];
        int s = src[i];
        int pos = atomicAdd(&row_ptr[d], 1) + partials[d >> 8];
        float w = dinv[s] * dinv[d];
        unsigned int rec = ((unsigned int)__half_as_ushort(__float2half_rn(w)) << 16)
                         | (unsigned int)s;
        edges[pos] = rec;
    }
}

// ---------- W1 -> W1^T fp16 ----------
__global__ __launch_bounds__(256) void wt_prep_kernel(const float* __restrict__ W1,
                                                      _Float16* __restrict__ WT) {
    int idx = blockIdx.x * 256 + threadIdx.x;
    if (idx < 128 * 128) {
        int k = idx >> 7, j = idx & 127;
        WT[j * 128 + k] = (_Float16)W1[idx];
    }
}

// ---------- GEMM1 (MFMA): h1 = X @ W1, f16 out ----------
__global__ __launch_bounds__(256) void gemm1_mfma_kernel(const float* __restrict__ X,
                                                         const _Float16* __restrict__ WT,
                                                         __half* __restrict__ H, int N) {
    __shared__ _Float16 As[64][136];

    int row0 = blockIdx.x * 64;
    {
        int r = threadIdx.x >> 2;
        int c0 = (threadIdx.x & 3) * 32;
        int row = row0 + r;
        if (row < N) {
            const float4* srcp = (const float4*)(X + (size_t)row * 128 + c0);
#pragma unroll
            for (int i = 0; i < 8; ++i) {
                float4 v = srcp[i];
                f16x4 h = {(_Float16)v.x, (_Float16)v.y, (_Float16)v.z, (_Float16)v.w};
                *(f16x4*)&As[r][c0 + 4 * i] = h;
            }
        } else {
            f16x4 z = {};
#pragma unroll
            for (int i = 0; i < 8; ++i) *(f16x4*)&As[r][c0 + 4 * i] = z;
        }
    }
    __syncthreads();

    int wave = threadIdx.x >> 6;
    int lane = threadIdx.x & 63;
    int l15 = lane & 15;
    int k0 = (lane >> 4) * 8;
    int arow = wave * 16 + l15;

    f32x4 acc[8] = {};
#pragma unroll
    for (int ks = 0; ks < 4; ++ks) {
        f16x8 a = *(const f16x8*)&As[arow][ks * 32 + k0];
#pragma unroll
        for (int t = 0; t < 8; ++t) {
            f16x8 b = *(const f16x8*)(WT + (size_t)(t * 16 + l15) * 128 + ks * 32 + k0);
            acc[t] = __builtin_amdgcn_mfma_f32_16x16x32_f16(a, b, acc[t], 0, 0, 0);
        }
    }

    int rbase = row0 + wave * 16 + (lane >> 4) * 4;
#pragma unroll
    for (int t = 0; t < 8; ++t) {
#pragma unroll
        for (int r = 0; r < 4; ++r) {
            int row = rbase + r;
            if (row < N) H[(size_t)row * 128 + t * 16 + l15] = __float2half(acc[t][r]);
        }
    }
}

// ---------- gather1 fused: agg(h1) -> +b1 -> LN -> ReLU -> @W2 -> h3 (fp16) ----------
__global__ __launch_bounds__(256) void gather1_fused_kernel(
    const __half* __restrict__ h1, const float* __restrict__ dinv,
    const int* __restrict__ row_ptr, const int* __restrict__ counts,
    const int* __restrict__ partials, const unsigned int* __restrict__ edges,
    const float* __restrict__ b1, const float* __restrict__ g1,
    const float* __restrict__ beta1, const float* __restrict__ W2,
    __half* __restrict__ h3, int N) {
    __shared__ float lds[4][K_DIM];
    int wave = threadIdx.x >> 6;
    int lane = threadIdx.x & 63;
    int node = blockIdx.x * 4 + wave;
    if (node >= N) return;

    float dd = dinv[node];
    float2 acc = __half22float2(((const __half2*)(h1 + (size_t)node * 128))[lane]);
    acc.x *= dd * dd; acc.y *= dd * dd;

    int end = row_ptr[node] + partials[node >> 8];
    int beg = end - counts[node];
    beg = __builtin_amdgcn_readfirstlane(beg);
    end = __builtin_amdgcn_readfirstlane(end);

    int e = beg;
    // main: 16 unpredicated row loads in flight
    for (; e + 16 <= end; e += 16) {
        unsigned int rec[16];
#pragma unroll
        for (int i = 0; i < 16; ++i) rec[i] = edges[e + i];   // uniform -> s_load
        __half2 v[16];
#pragma unroll
        for (int i = 0; i < 16; ++i)
            v[i] = ((const __half2*)(h1 + (size_t)(rec[i] & 0xFFFFu) * 128))[lane];
#pragma unroll
        for (int i = 0; i < 16; ++i) {
            float w = wbits(rec[i]);
            float2 f = __half22float2(v[i]);
            acc.x = fmaf(f.x, w, acc.x);
            acc.y = fmaf(f.y, w, acc.y);
        }
    }
    // tail: 8-wide, predicated (pad rows are zero-weighted)
    for (; e < end; e += 8) {
        unsigned int rec[8];
#pragma unroll
        for (int i = 0; i < 8; ++i) rec[i] = edges[e + i];
        __half2 v[8];
#pragma unroll
        for (int i = 0; i < 8; ++i)
            v[i] = ((const __half2*)(h1 + (size_t)(rec[i] & 0xFFFFu) * 128))[lane];
#pragma unroll
        for (int i = 0; i < 8; ++i) {
            float w = (e + i < end) ? wbits(rec[i]) : 0.0f;
            float2 f = __half22float2(v[i]);
            acc.x = fmaf(f.x, w, acc.x);
            acc.y = fmaf(f.y, w, acc.y);
        }
    }

    // bias + LN + ReLU
    float2 bb = ((const float2*)b1)[lane];
    acc.x += bb.x; acc.y += bb.y;
    float s = acc.x + acc.y;
    for (int off = 32; off; off >>= 1) s += __shfl_xor(s, off);
    float mu = s * (1.0f / 128.0f);
    float dx = acc.x - mu, dy = acc.y - mu;
    float q = dx * dx + dy * dy;
    for (int off = 32; off; off >>= 1) q += __shfl_xor(q, off);
    float rstd = rsqrtf(q * (1.0f / 128.0f) + 1e-5f);
    float2 gg = ((const float2*)g1)[lane];
    float2 be = ((const float2*)beta1)[lane];
    float ox = fmaxf(fmaf(dx * rstd, gg.x, be.x), 0.0f);
    float oy = fmaxf(fmaf(dy * rstd, gg.y, be.y), 0.0f);

    // 128x64 matvec via LDS broadcast; lane owns output col = lane
    ((float2*)&lds[wave][0])[lane] = make_float2(ox, oy);
    float o = 0.0f;
#pragma unroll 8
    for (int k = 0; k < K_DIM; k += 4) {
        float4 vv = *(const float4*)&lds[wave][k];
        o = fmaf(vv.x, W2[(size_t)(k + 0) * 64 + lane], o);
        o = fmaf(vv.y, W2[(size_t)(k + 1) * 64 + lane], o);
        o = fmaf(vv.z, W2[(size_t)(k + 2) * 64 + lane], o);
        o = fmaf(vv.w, W2[(size_t)(k + 3) * 64 + lane], o);
    }
    h3[(size_t)node * 64 + lane] = __float2half(o);
}

// ---------- gather2 fused: agg(h3) -> +b2 -> LN -> ReLU -> L2 -> out ----------
__global__ __launch_bounds__(256) void gather2_fused_kernel(
    const __half* __restrict__ h3, const float* __restrict__ dinv,
    const int* __restrict__ row_ptr, const int* __restrict__ counts,
    const int* __restrict__ partials, const unsigned int* __restrict__ edges,
    const float* __restrict__ b2, const float* __restrict__ g2,
    const float* __restrict__ beta2, float* __restrict__ out, int N) {
    int wave = threadIdx.x >> 6;
    int lane = threadIdx.x & 63;
    int node = blockIdx.x * 4 + wave;
    if (node >= N) return;

    float dd = dinv[node];
    float acc = __half2float(h3[(size_t)node * 64 + lane]) * dd * dd;

    int end = row_ptr[node] + partials[node >> 8];
    int beg = end - counts[node];
    beg = __builtin_amdgcn_readfirstlane(beg);
    end = __builtin_amdgcn_readfirstlane(end);

    int e = beg;
    for (; e + 16 <= end; e += 16) {
        unsigned int rec[16];
#pragma unroll
        for (int i = 0; i < 16; ++i) rec[i] = edges[e + i];
        __half v[16];
#pragma unroll
        for (int i = 0; i < 16; ++i)
            v[i] = h3[(size_t)(rec[i] & 0xFFFFu) * 64 + lane];
#pragma unroll
        for (int i = 0; i < 16; ++i)
            acc = fmaf(__half2float(v[i]), wbits(rec[i]), acc);
    }
    for (; e < end; e += 8) {
        unsigned int rec[8];
#pragma unroll
        for (int i = 0; i < 8; ++i) rec[i] = edges[e + i];
        __half v[8];
#pragma unroll
        for (int i = 0; i < 8; ++i)
            v[i] = h3[(size_t)(rec[i] & 0xFFFFu) * 64 + lane];
#pragma unroll
        for (int i = 0; i < 8; ++i) {
            float w = (e + i < end) ? wbits(rec[i]) : 0.0f;
            acc = fmaf(__half2float(v[i]), w, acc);
        }
    }

    float v = acc + b2[lane];
    float s = v;
    for (int off = 32; off; off >>= 1) s += __shfl_xor(s, off);
    float mu = s * (1.0f / 64.0f);
    float d = v - mu;
    float q = d * d;
    for (int off = 32; off; off >>= 1) q += __shfl_xor(q, off);
    float rstd = rsqrtf(q * (1.0f / 64.0f) + 1e-5f);
    float o = fmaxf(fmaf(d * rstd, g2[lane], beta2[lane]), 0.0f);
    float q2 = o * o;
    for (int off = 32; off; off >>= 1) q2 += __shfl_xor(q2, off);
    float nrm = sqrtf(q2);
    out[(size_t)node * 64 + lane] = o / fmaxf(nrm, 1e-12f);
}

extern "C" void kernel_launch(void* const* d_in, const int* in_sizes, int n_in,
                              void* d_out, int out_size, void* d_ws, size_t ws_size,
                              hipStream_t stream) {
    const float* x     = (const float*)d_in[0];
    const int*   ei    = (const int*)d_in[1];
    const float* W1    = (const float*)d_in[2];
    const float* b1    = (const float*)d_in[3];
    const float* g1    = (const float*)d_in[4];
    const float* beta1 = (const float*)d_in[5];
    const float* W2    = (const float*)d_in[6];
    const float* b2    = (const float*)d_in[7];
    const float* g2    = (const float*)d_in[8];
    const float* beta2 = (const float*)d_in[9];

    const int N = in_sizes[0] / 128;
    const int E = in_sizes[1] / 2;
    const int* src = ei;       // edge_index[0]
    const int* dst = ei + E;   // edge_index[1]
    float* out = (float*)d_out;

    // Workspace (~23 MB)
    char* p = (char*)d_ws;
    auto alloc = [&](size_t bytes) { char* r = p; p += (bytes + 255) & ~(size_t)255; return r; };
    int*          counts   = (int*)alloc((size_t)N * 4);
    int*          row_ptr  = (int*)alloc((size_t)N * 4);
    int*          partials = (int*)alloc(256 * 4);
    float*        dinv     = (float*)alloc((size_t)N * 4);
    unsigned int* edges    = (unsigned int*)alloc(((size_t)E + 64) * 4);  // +pad
    _Float16*     WT       = (_Float16*)alloc(128 * 128 * 2);
    __half*       h1       = (__half*)alloc((size_t)N * 128 * 2);
    __half*       h3       = (__half*)alloc((size_t)N * 64 * 2);

    const int nb_nodes = (N + 255) / 256;
    const int nb_edges = (E + 255) / 256;
    const int nb_wave_nodes = (N + 3) / 4;

    // CSR build + dinv + packed 4-byte edge records (+ zeroed pad)
    hipMemsetAsync(counts, 0, (size_t)N * 4, stream);
    hipMemsetAsync(edges + E, 0, 64 * 4, stream);
    hist_kernel<<<nb_edges, 256, 0, stream>>>(dst, counts, E);
    scan_block_kernel<<<nb_nodes, 256, 0, stream>>>(counts, row_ptr, partials, dinv, N);
    scan_partials_kernel<<<1, 256, 0, stream>>>(partials, nb_nodes);
    fill_kernel<<<nb_edges, 256, 0, stream>>>(src, dst, dinv, row_ptr, partials, edges, E);

    // layer 1 GEMM (MFMA, f16 out)
    wt_prep_kernel<<<64, 256, 0, stream>>>(W1, WT);
    gemm1_mfma_kernel<<<(N + 63) / 64, 256, 0, stream>>>(x, WT, h1, N);

    // layer 1 aggregate + LN + ReLU + layer 2 GEMM (fused)
    gather1_fused_kernel<<<nb_wave_nodes, 256, 0, stream>>>(
        h1, dinv, row_ptr, counts, partials, edges, b1, g1, beta1, W2, h3, N);

    // layer 2 aggregate + LN + ReLU + L2 (fused)
    gather2_fused_kernel<<<nb_wave_nodes, 256, 0, stream>>>(
        h3, dinv, row_ptr, counts, partials, edges, b2, g2, beta2, out, N);
}